// Round 7
// baseline (1366.943 us; speedup 1.0000x reference)
//
#include <hip/hip_runtime.h>

typedef unsigned short ushort;
typedef unsigned int uint;
typedef __bf16 bf16_t;
typedef bf16_t bf16x8 __attribute__((ext_vector_type(8)));
typedef float f32x4 __attribute__((ext_vector_type(4)));

#define B_ 2048
#define T_ 512
#define D_ 5
#define H_ 128
#define C_ 10
#define BT 16      // batch tile per producer/consumer pair
#define BLK 512    // 8 waves, 2 waves/SIMD
#define NP 128     // pair count
#define CH 16      // pipeline chunk (steps per sync)
#define H0STR 168  // producer LDS row stride in ushorts (h0 128 + x cols + pad)
#define H1STR 136  // h1 row stride (128 + 8 pad)

static __device__ __forceinline__ float b2f(ushort u) {
    return __builtin_bit_cast(float, ((uint)u) << 16);
}
static __device__ __forceinline__ ushort f2b(float f) {
    uint u = __builtin_bit_cast(uint, f);
    u += 0x7FFFu + ((u >> 16) & 1u);   // RNE
    return (ushort)(u >> 16);
}
// inf-safe: exp->inf => rcp->0 => sigmoid->0/1, tanh->+-1
static __device__ __forceinline__ float sigf(float x) {
    return __builtin_amdgcn_rcpf(1.0f + __expf(-x));
}
static __device__ __forceinline__ float tanhf_(float x) {
    return 1.0f - 2.0f * __builtin_amdgcn_rcpf(1.0f + __expf(2.0f * x));
}
static __device__ __forceinline__ float ldf(const void* p, long i, bool m32) {
    return m32 ? ((const float*)p)[i] : b2f(((const ushort*)p)[i]);
}
static __device__ __forceinline__ bf16x8 ld16(const ushort* p) {
    return __builtin_bit_cast(bf16x8, *(const uint4*)p);
}
static __device__ __forceinline__ bf16x8 ldfrag(const void* p, long idx, bool m32) {
    if (!m32) return ld16((const ushort*)p + idx);
    const float* f = (const float*)p + idx;
    union { ushort u[8]; bf16x8 v; } r;
#pragma unroll
    for (int j = 0; j < 8; ++j) r.u[j] = f2b(f[j]);
    return r.v;
}
static __device__ __forceinline__ f32x4 splat4(float v) {
    f32x4 r = {v, v, v, v};
    return r;
}

// ---- dtype detector (proven R2-R6; picks f32)
__global__ void detect_dtype(const ushort* __restrict__ w, int* __restrict__ flag) {
    __shared__ int cnt;
    if (threadIdx.x == 0) cnt = 0;
    __syncthreads();
    int local = 0;
    for (int i = threadIdx.x; i < 16384; i += 256)
        if ((uint)(w[i] & 0x7F80u) >= 0x4180u) ++local;   // |v| >= 16
    atomicAdd(&cnt, local);
    __syncthreads();
    if (threadIdx.x == 0) *flag = (cnt > 512) ? 1 : 0;
}

// ---- zero pipeline progress flags each launch (d_ws is poisoned)
__global__ void init_flags(int* __restrict__ prog) {
    prog[threadIdx.x] = 0;   // 256 ints: prog_p[128] | prog_c[128]
}

// =====================================================================
// block p<NP = layer-0 producer; block NP+p = layer-1 consumer+classifier.
// h0 streamed via per-pair ring FIFO (F slots, row-major [row][col]) in d_ws.
// Consumer loads its MFMA A-fragments DIRECTLY from the FIFO (no LDS staging).
// =====================================================================
__global__ __launch_bounds__(BLK, 2) void lstm2_pipe(
    const void* __restrict__ x,
    const void* __restrict__ wih0, const void* __restrict__ whh0,
    const void* __restrict__ bih0, const void* __restrict__ bhh0,
    const void* __restrict__ wih1, const void* __restrict__ whh1,
    const void* __restrict__ bih1, const void* __restrict__ bhh1,
    const void* __restrict__ cw1, const void* __restrict__ cb1,
    const void* __restrict__ cw2, const void* __restrict__ cb2,
    const int* __restrict__ flag,
    ushort* __restrict__ fifo, int* __restrict__ prog_p, int* __restrict__ prog_c,
    int F, void* __restrict__ out)
{
    __shared__ __align__(16) ushort sA[2][BT * H0STR]; // producer: h0 + x staging
    __shared__ __align__(16) ushort sB[2][BT * H1STR]; // consumer: h1 recurrence
    __shared__ float rs[BT * 64];                      // consumer: classifier hidden

    const bool m32 = (*flag) != 0;
    const int tid  = threadIdx.x;
    const int w    = tid >> 6;
    const int lane = tid & 63;
    const int quad = lane >> 4;
    const int l16  = lane & 15;

    if ((int)blockIdx.x < NP) {
        // ================= PRODUCER: layer 0 =================
        const int p   = blockIdx.x;
        const int bt0 = p * BT;
        ushort* myfifo = fifo + (long)p * F * (BT * H_);

        // stage x(0) into sA[0] cols 128..159; zeros into sA[1]
        for (int i = tid; i < BT * 32; i += BLK) {
            int row = i >> 5, cc = i & 31;
            ushort v0 = (cc < 5) ? f2b(ldf(x, ((long)(bt0 + row) * T_) * D_ + cc, m32))
                                 : (ushort)0;
            sA[0][row * H0STR + 128 + cc] = v0;
            sA[1][row * H0STR + 128 + cc] = 0;
        }

        // weights: w_hh0 frags + x-tile frags (~140 regs/wave)
        bf16x8 wh0c[4][4];
        bf16x8 xbf[4];
        float  b0v[4];
#pragma unroll
        for (int g = 0; g < 4; ++g) {
            const int n = g * 128 + w * 16 + l16;
#pragma unroll
            for (int kt = 0; kt < 4; ++kt)
                wh0c[g][kt] = ldfrag(whh0, (long)n * 128 + kt * 32 + quad * 8, m32);
            union { ushort u[8]; bf16x8 v; } xt;
#pragma unroll
            for (int j = 0; j < 8; ++j) xt.u[j] = 0;
            if (quad == 0) {
#pragma unroll
                for (int j = 0; j < 5; ++j) xt.u[j] = f2b(ldf(wih0, (long)n * D_ + j, m32));
            }
            xbf[g] = xt.v;
            b0v[g] = ldf(bih0, n, m32) + ldf(bhh0, n, m32);
        }
        __syncthreads();

        bf16x8 h0f[4];
        {
            uint4 z = make_uint4(0, 0, 0, 0);
            h0f[0] = h0f[1] = h0f[2] = h0f[3] = __builtin_bit_cast(bf16x8, z);
        }
        f32x4 c0 = splat4(0.f);
        const int xr = tid / 5, xc = tid - (tid / 5) * 5;
        long xoff = ((long)(bt0 + xr) * T_ + 1) * D_ + xc;  // x(1), pointer-bumped
        const int fbase = w * 16 + l16;                      // FIFO col
        const int frow0 = quad * 4;                          // FIFO first row

#pragma unroll 1
        for (int t = 0; t < T_; ++t) {
            const int rb = t & 1, wb = (t + 1) & 1;
            if ((t & (CH - 1)) == 0 && t > 0) {
                if (tid == 0) {
                    __hip_atomic_store(&prog_p[p], t, __ATOMIC_RELEASE,
                                       __HIP_MEMORY_SCOPE_AGENT);
                    int need = t + CH - F;   // ring WAR throttle
                    if (need > 0)
                        while (__hip_atomic_load(&prog_c[p], __ATOMIC_ACQUIRE,
                                                 __HIP_MEMORY_SCOPE_AGENT) < need)
                            __builtin_amdgcn_s_sleep(2);
                }
                __syncthreads();
            }
            float xv = 0.f;
            const bool stage = (tid < 80) && (t < T_ - 1);
            if (stage) { xv = ldf(x, xoff, m32); xoff += D_; }

            f32x4 a[4];
#pragma unroll
            for (int g = 0; g < 4; ++g) a[g] = splat4(b0v[g]);
#pragma unroll
            for (int kt = 0; kt < 4; ++kt)
#pragma unroll
                for (int g = 0; g < 4; ++g)
                    a[g] = __builtin_amdgcn_mfma_f32_16x16x32_bf16(
                        h0f[kt], wh0c[g][kt], a[g], 0, 0, 0);
            {
                bf16x8 ha4 = ld16(&sA[rb][l16 * H0STR + 128 + quad * 8]);
#pragma unroll
                for (int g = 0; g < 4; ++g)
                    a[g] = __builtin_amdgcn_mfma_f32_16x16x32_bf16(
                        ha4, xbf[g], a[g], 0, 0, 0);
            }
            ushort* fs = myfifo + ((long)(t & (F - 1)) * (BT * H_));
#pragma unroll
            for (int r = 0; r < 4; ++r) {
                float iv = sigf(a[0][r]), fv = sigf(a[1][r]);
                float gv = tanhf_(a[2][r]), ov = sigf(a[3][r]);
                float cv = fv * c0[r] + iv * gv;
                c0[r] = cv;
                ushort hv = f2b(ov * tanhf_(cv));
                sA[wb][(frow0 + r) * H0STR + fbase] = hv;
                fs[(frow0 + r) * H_ + fbase] = hv;        // FIFO (drained by barrier)
            }
            if (stage) sA[wb][xr * H0STR + 128 + xc] = f2b(xv);
            __syncthreads();
#pragma unroll
            for (int kt = 0; kt < 4; ++kt)
                h0f[kt] = ld16(&sA[wb][l16 * H0STR + kt * 32 + quad * 8]);
        }
        if (tid == 0)
            __hip_atomic_store(&prog_p[p], T_, __ATOMIC_RELEASE,
                               __HIP_MEMORY_SCOPE_AGENT);
    } else {
        // ================= CONSUMER: layer 1 + classifier =================
        const int p   = blockIdx.x - NP;
        const int bt0 = p * BT;
        const ushort* myfifo = fifo + (long)p * F * (BT * H_);

        // zero h1(-1)
        for (int i = tid; i < BT * H_; i += BLK) {
            int row = i >> 7, cc = i & 127;
            sB[0][row * H1STR + cc] = 0;
        }

        // weights: w_ih1 + w_hh1 frags (~210 regs/wave incl. working set)
        bf16x8 wi1f[4][4], wh1f[4][4];
        float  b1v[4];
#pragma unroll
        for (int g = 0; g < 4; ++g) {
            const int n = g * 128 + w * 16 + l16;
#pragma unroll
            for (int kt = 0; kt < 4; ++kt) {
                wi1f[g][kt] = ldfrag(wih1, (long)n * 128 + kt * 32 + quad * 8, m32);
                wh1f[g][kt] = ldfrag(whh1, (long)n * 128 + kt * 32 + quad * 8, m32);
            }
            b1v[g] = ldf(bih1, n, m32) + ldf(bhh1, n, m32);
        }

        // wait for the first two chunks
        if (tid == 0) {
            while (__hip_atomic_load(&prog_p[p], __ATOMIC_ACQUIRE,
                                     __HIP_MEMORY_SCOPE_AGENT) < 2 * CH)
                __builtin_amdgcn_s_sleep(2);
        }
        __syncthreads();

        // per-lane A-fragment offset within a FIFO slot
        const int foff = l16 * H_ + quad * 8;
        bf16x8 h0f[4];
#pragma unroll
        for (int kt = 0; kt < 4; ++kt)
            h0f[kt] = ld16(myfifo + foff + kt * 32);   // slot 0

        f32x4 c1 = splat4(0.f);

#pragma unroll 1
        for (int t = 0; t < T_; ++t) {
            const int rb = t & 1, wb = (t + 1) & 1;
            // chunk boundary BEFORE prefetching into the next chunk:
            // acquire-invalidate precedes every read of newly-ready slots.
            if (((t + 1) & (CH - 1)) == 0 && t + 1 < T_) {
                if (tid == 0) {
                    int target = t + 1 + CH;
                    if (target > T_) target = T_;
                    while (__hip_atomic_load(&prog_p[p], __ATOMIC_ACQUIRE,
                                             __HIP_MEMORY_SCOPE_AGENT) < target)
                        __builtin_amdgcn_s_sleep(2);
                    __hip_atomic_store(&prog_c[p], t + 1, __ATOMIC_RELEASE,
                                       __HIP_MEMORY_SCOPE_AGENT);
                }
                __syncthreads();
            }
            // prefetch h0(t+1) A-frags straight from FIFO (global, one step deep)
            bf16x8 h0n[4];
            const bool hn = (t + 1 < T_);
            if (hn) {
                const ushort* fsn = myfifo + ((long)((t + 1) & (F - 1)) * (BT * H_)) + foff;
#pragma unroll
                for (int kt = 0; kt < 4; ++kt)
                    h0n[kt] = ld16(fsn + kt * 32);
            }

            f32x4 a[4];
#pragma unroll
            for (int g = 0; g < 4; ++g) a[g] = splat4(b1v[g]);
#pragma unroll
            for (int kt = 0; kt < 4; ++kt)
#pragma unroll
                for (int g = 0; g < 4; ++g)
                    a[g] = __builtin_amdgcn_mfma_f32_16x16x32_bf16(
                        h0f[kt], wi1f[g][kt], a[g], 0, 0, 0);
#pragma unroll
            for (int kt = 0; kt < 4; ++kt) {
                bf16x8 hb = ld16(&sB[rb][l16 * H1STR + kt * 32 + quad * 8]);
#pragma unroll
                for (int g = 0; g < 4; ++g)
                    a[g] = __builtin_amdgcn_mfma_f32_16x16x32_bf16(
                        hb, wh1f[g][kt], a[g], 0, 0, 0);
            }
#pragma unroll
            for (int r = 0; r < 4; ++r) {
                float iv = sigf(a[0][r]), fv = sigf(a[1][r]);
                float gv = tanhf_(a[2][r]), ov = sigf(a[3][r]);
                float cv = fv * c1[r] + iv * gv;
                c1[r] = cv;
                sB[wb][(quad * 4 + r) * H1STR + w * 16 + l16] = f2b(ov * tanhf_(cv));
            }
            if (hn) {
#pragma unroll
                for (int kt = 0; kt < 4; ++kt) h0f[kt] = h0n[kt];
            }
            __syncthreads();
        }

        // h1(T-1) is in sB[0]  (t=511 wrote wb=0)
        if (tid < 256) {
            int m = tid >> 4, j0 = (tid & 15) * 4;
            float s0 = ldf(cb1, j0, m32), s1 = ldf(cb1, j0 + 1, m32);
            float s2 = ldf(cb1, j0 + 2, m32), s3 = ldf(cb1, j0 + 3, m32);
            const ushort* hr = &sB[0][m * H1STR];
#pragma unroll 4
            for (int k = 0; k < 128; ++k) {
                float hv = b2f(hr[k]);
                s0 += hv * ldf(cw1, (long)j0 * 128 + k, m32);
                s1 += hv * ldf(cw1, (long)(j0 + 1) * 128 + k, m32);
                s2 += hv * ldf(cw1, (long)(j0 + 2) * 128 + k, m32);
                s3 += hv * ldf(cw1, (long)(j0 + 3) * 128 + k, m32);
            }
            rs[m * 64 + j0]     = fmaxf(s0, 0.f);
            rs[m * 64 + j0 + 1] = fmaxf(s1, 0.f);
            rs[m * 64 + j0 + 2] = fmaxf(s2, 0.f);
            rs[m * 64 + j0 + 3] = fmaxf(s3, 0.f);
        }
        __syncthreads();
        if (tid < 160) {
            int m = tid / 10, cc = tid - m * 10;
            float s = ldf(cb2, cc, m32);
#pragma unroll
            for (int j = 0; j < 64; ++j)
                s += rs[m * 64 + j] * ldf(cw2, (long)cc * 64 + j, m32);
            long oi = (long)(bt0 + m) * C_ + cc;
            if (m32) ((float*)out)[oi] = s; else ((ushort*)out)[oi] = f2b(s);
        }
        for (int idx = tid; idx < BT * H_; idx += BLK) {
            int m = idx >> 7, k = idx & 127;
            float v = b2f(sB[0][m * H1STR + k]);
            long oi = (long)B_ * C_ + (long)(bt0 + m) * H_ + k;
            if (m32) ((float*)out)[oi] = v; else ((ushort*)out)[oi] = f2b(v);
        }
    }
}

// =====================================================================
// Fallback: proven R5 monolithic kernel (when ws too small for the FIFO)
// =====================================================================
__global__ __launch_bounds__(BLK, 2) void lstm2_mono(
    const void* __restrict__ x,
    const void* __restrict__ wih0, const void* __restrict__ whh0,
    const void* __restrict__ bih0, const void* __restrict__ bhh0,
    const void* __restrict__ wih1, const void* __restrict__ whh1,
    const void* __restrict__ bih1, const void* __restrict__ bhh1,
    const void* __restrict__ cw1, const void* __restrict__ cb1,
    const void* __restrict__ cw2, const void* __restrict__ cb2,
    const int* __restrict__ flag, void* __restrict__ out)
{
    __shared__ __align__(16) ushort h0s[2][BT * H0STR];
    __shared__ __align__(16) ushort h1s[2][BT * H1STR];
    __shared__ float rs[BT * 64];
    __shared__ uint4 xstash[4 * 8 * 64];

    const bool m32 = (*flag) != 0;
    const int tid  = threadIdx.x;
    const int w    = tid >> 6;
    const int lane = tid & 63;
    const int quad = lane >> 4;
    const int l16  = lane & 15;
    const int bt0  = blockIdx.x * BT;

    for (int i = tid; i < BT * 32; i += BLK) {
        int row = i >> 5, cc = i & 31;
        ushort v0 = (cc < 5) ? f2b(ldf(x, ((long)(bt0 + row) * T_) * D_ + cc, m32)) : (ushort)0;
        h0s[0][row * H0STR + 128 + cc] = v0;
        h0s[1][row * H0STR + 128 + cc] = 0;
    }
    for (int i = tid; i < BT * H_; i += BLK) {
        int row = i >> 7, cc = i & 127;
        h1s[1][row * H1STR + cc] = 0;
    }

    bf16x8 wh0c[4][4], wi1f[4][4], wh1f[4][4];
    float  b0v[4], b1v[4];
#pragma unroll
    for (int g = 0; g < 4; ++g) {
        const int n = g * 128 + w * 16 + l16;
#pragma unroll
        for (int kt = 0; kt < 4; ++kt) {
            wh0c[g][kt] = ldfrag(whh0, (long)n * 128 + kt * 32 + quad * 8, m32);
            wi1f[g][kt] = ldfrag(wih1, (long)n * 128 + kt * 32 + quad * 8, m32);
            wh1f[g][kt] = ldfrag(whh1, (long)n * 128 + kt * 32 + quad * 8, m32);
        }
        union { ushort u[8]; uint4 q; } xt;
        xt.q = make_uint4(0, 0, 0, 0);
        if (quad == 0) {
#pragma unroll
            for (int j = 0; j < 5; ++j) xt.u[j] = f2b(ldf(wih0, (long)n * D_ + j, m32));
        }
        xstash[(g * 8 + w) * 64 + lane] = xt.q;
        b0v[g] = ldf(bih0, n, m32) + ldf(bhh0, n, m32);
        b1v[g] = ldf(bih1, n, m32) + ldf(bhh1, n, m32);
    }
    __syncthreads();

    bf16x8 h0f[4];
    {
        uint4 z = make_uint4(0, 0, 0, 0);
        h0f[0] = h0f[1] = h0f[2] = h0f[3] = __builtin_bit_cast(bf16x8, z);
    }
    f32x4 c0 = splat4(0.f), c1 = splat4(0.f);
    const int xr = tid / 5, xc = tid - (tid / 5) * 5;

#pragma unroll 1
    for (int t = 0; t < T_; ++t) {
        const int wb = (t + 1) & 1, rb = t & 1;
        float xv = 0.f;
        const bool stage = (tid < 80) && (t < T_ - 1);
        if (stage) xv = ldf(x, ((long)(bt0 + xr) * T_ + (t + 1)) * D_ + xc, m32);

        f32x4 a[4];
#pragma unroll
        for (int g = 0; g < 4; ++g) a[g] = splat4(b0v[g]);
#pragma unroll
        for (int kt = 0; kt < 4; ++kt)
#pragma unroll
            for (int g = 0; g < 4; ++g)
                a[g] = __builtin_amdgcn_mfma_f32_16x16x32_bf16(
                    h0f[kt], wh0c[g][kt], a[g], 0, 0, 0);
        {
            bf16x8 ha4 = ld16(&h0s[rb][l16 * H0STR + 128 + quad * 8]);
#pragma unroll
            for (int g = 0; g < 4; ++g) {
                bf16x8 xb = __builtin_bit_cast(bf16x8, xstash[(g * 8 + w) * 64 + lane]);
                a[g] = __builtin_amdgcn_mfma_f32_16x16x32_bf16(ha4, xb, a[g], 0, 0, 0);
            }
        }
        ushort h0w[4];
#pragma unroll
        for (int r = 0; r < 4; ++r) {
            float iv = sigf(a[0][r]), fv = sigf(a[1][r]);
            float gv = tanhf_(a[2][r]), ov = sigf(a[3][r]);
            float cv = fv * c0[r] + iv * gv;
            c0[r] = cv;
            h0w[r] = f2b(ov * tanhf_(cv));
        }
#pragma unroll
        for (int r = 0; r < 4; ++r)
            h0s[wb][(quad * 4 + r) * H0STR + w * 16 + l16] = h0w[r];
        if (stage) h0s[wb][xr * H0STR + 128 + xc] = f2b(xv);
        __syncthreads();
#pragma unroll
        for (int kt = 0; kt < 4; ++kt)
            h0f[kt] = ld16(&h0s[wb][l16 * H0STR + kt * 32 + quad * 8]);

#pragma unroll
        for (int g = 0; g < 4; ++g) a[g] = splat4(b1v[g]);
#pragma unroll
        for (int kt = 0; kt < 4; ++kt)
#pragma unroll
            for (int g = 0; g < 4; ++g)
                a[g] = __builtin_amdgcn_mfma_f32_16x16x32_bf16(
                    h0f[kt], wi1f[g][kt], a[g], 0, 0, 0);
#pragma unroll
        for (int kt = 0; kt < 4; ++kt) {
            bf16x8 hb = ld16(&h1s[wb][l16 * H1STR + kt * 32 + quad * 8]);
#pragma unroll
            for (int g = 0; g < 4; ++g)
                a[g] = __builtin_amdgcn_mfma_f32_16x16x32_bf16(
                    hb, wh1f[g][kt], a[g], 0, 0, 0);
        }
#pragma unroll
        for (int r = 0; r < 4; ++r) {
            float iv = sigf(a[0][r]), fv = sigf(a[1][r]);
            float gv = tanhf_(a[2][r]), ov = sigf(a[3][r]);
            float cv = fv * c1[r] + iv * gv;
            c1[r] = cv;
            h1s[wb ^ 1][(quad * 4 + r) * H1STR + w * 16 + l16] = f2b(ov * tanhf_(cv));
        }
    }
    __syncthreads();

    if (tid < 256) {
        int m = tid >> 4, j0 = (tid & 15) * 4;
        float s0 = ldf(cb1, j0, m32), s1 = ldf(cb1, j0 + 1, m32);
        float s2 = ldf(cb1, j0 + 2, m32), s3 = ldf(cb1, j0 + 3, m32);
        const ushort* hr = &h1s[1][m * H1STR];
#pragma unroll 4
        for (int k = 0; k < 128; ++k) {
            float hv = b2f(hr[k]);
            s0 += hv * ldf(cw1, (long)j0 * 128 + k, m32);
            s1 += hv * ldf(cw1, (long)(j0 + 1) * 128 + k, m32);
            s2 += hv * ldf(cw1, (long)(j0 + 2) * 128 + k, m32);
            s3 += hv * ldf(cw1, (long)(j0 + 3) * 128 + k, m32);
        }
        rs[m * 64 + j0]     = fmaxf(s0, 0.f);
        rs[m * 64 + j0 + 1] = fmaxf(s1, 0.f);
        rs[m * 64 + j0 + 2] = fmaxf(s2, 0.f);
        rs[m * 64 + j0 + 3] = fmaxf(s3, 0.f);
    }
    __syncthreads();
    if (tid < 160) {
        int m = tid / 10, cc = tid - m * 10;
        float s = ldf(cb2, cc, m32);
#pragma unroll
        for (int j = 0; j < 64; ++j) s += rs[m * 64 + j] * ldf(cw2, (long)cc * 64 + j, m32);
        long oi = (long)(bt0 + m) * C_ + cc;
        if (m32) ((float*)out)[oi] = s; else ((ushort*)out)[oi] = f2b(s);
    }
    for (int idx = tid; idx < BT * H_; idx += BLK) {
        int m = idx >> 7, k = idx & 127;
        float v = b2f(h1s[1][m * H1STR + k]);
        long oi = (long)B_ * C_ + (long)(bt0 + m) * H_ + k;
        if (m32) ((float*)out)[oi] = v; else ((ushort*)out)[oi] = f2b(v);
    }
}

extern "C" void kernel_launch(void* const* d_in, const int* in_sizes, int n_in,
                              void* d_out, int out_size, void* d_ws, size_t ws_size,
                              hipStream_t stream) {
    (void)in_sizes; (void)n_in; (void)out_size;
    int* prog  = (int*)d_ws;                       // prog_p[128] | prog_c[128]
    int* flag  = (int*)((char*)d_ws + 4096);
    ushort* fifo = (ushort*)((char*)d_ws + 8192);

    hipLaunchKernelGGL(detect_dtype, dim3(1), dim3(256), 0, stream,
                       (const ushort*)d_in[2], flag);

    const size_t slot = (size_t)NP * BT * H_ * sizeof(ushort); // all pairs, 1 step
    int F = 0;
    if (ws_size >= 8192 + 64 * slot) F = 64;

    if (F) {
        hipLaunchKernelGGL(init_flags, dim3(1), dim3(256), 0, stream, prog);
        hipLaunchKernelGGL(lstm2_pipe, dim3(2 * NP), dim3(BLK), 0, stream,
                           d_in[0], d_in[1], d_in[2], d_in[3], d_in[4],
                           d_in[5], d_in[6], d_in[7], d_in[8],
                           d_in[9], d_in[10], d_in[11], d_in[12],
                           (const int*)flag, fifo, prog, prog + NP, F, d_out);
    } else {
        hipLaunchKernelGGL(lstm2_mono, dim3(B_ / BT), dim3(BLK), 0, stream,
                           d_in[0], d_in[1], d_in[2], d_in[3], d_in[4],
                           d_in[5], d_in[6], d_in[7], d_in[8],
                           d_in[9], d_in[10], d_in[11], d_in[12],
                           (const int*)flag, d_out);
    }
}

// Round 8
// 1008.019 us; speedup vs baseline: 1.3561x; 1.3561x over previous
//
#include <hip/hip_runtime.h>

typedef unsigned short ushort;
typedef unsigned int uint;
typedef __bf16 bf16_t;
typedef bf16_t bf16x8 __attribute__((ext_vector_type(8)));
typedef float f32x4 __attribute__((ext_vector_type(4)));

#define B_ 2048
#define T_ 512
#define D_ 5
#define H_ 128
#define C_ 10
#define BT 16      // batch tile per producer/consumer pair
#define BLK 512    // 8 waves, 2 waves/SIMD
#define NP 128     // pair count
#define CH 8       // pipeline chunk (steps per sync) — R6-proven
#define H0STR 168  // sA row stride in ushorts (h0 128 + x cols + pad)
#define H1STR 136  // sB row stride (128 + 8 pad)

static __device__ __forceinline__ float b2f(ushort u) {
    return __builtin_bit_cast(float, ((uint)u) << 16);
}
static __device__ __forceinline__ ushort f2b(float f) {
    uint u = __builtin_bit_cast(uint, f);
    u += 0x7FFFu + ((u >> 16) & 1u);   // RNE
    return (ushort)(u >> 16);
}
// inf-safe: exp->inf => rcp->0 => sigmoid->0/1, tanh->+-1
static __device__ __forceinline__ float sigf(float x) {
    return __builtin_amdgcn_rcpf(1.0f + __expf(-x));
}
static __device__ __forceinline__ float tanhf_(float x) {
    return 1.0f - 2.0f * __builtin_amdgcn_rcpf(1.0f + __expf(2.0f * x));
}
static __device__ __forceinline__ float ldf(const void* p, long i, bool m32) {
    return m32 ? ((const float*)p)[i] : b2f(((const ushort*)p)[i]);
}
static __device__ __forceinline__ bf16x8 ld16(const ushort* p) {
    return __builtin_bit_cast(bf16x8, *(const uint4*)p);
}
static __device__ __forceinline__ bf16x8 ldfrag(const void* p, long idx, bool m32) {
    if (!m32) return ld16((const ushort*)p + idx);
    const float* f = (const float*)p + idx;
    union { ushort u[8]; bf16x8 v; } r;
#pragma unroll
    for (int j = 0; j < 8; ++j) r.u[j] = f2b(f[j]);
    return r.v;
}
static __device__ __forceinline__ f32x4 splat4(float v) {
    f32x4 r = {v, v, v, v};
    return r;
}

// ---- dtype detector (proven R2-R7; picks f32)
__global__ void detect_dtype(const ushort* __restrict__ w, int* __restrict__ flag) {
    __shared__ int cnt;
    if (threadIdx.x == 0) cnt = 0;
    __syncthreads();
    int local = 0;
    for (int i = threadIdx.x; i < 16384; i += 256)
        if ((uint)(w[i] & 0x7F80u) >= 0x4180u) ++local;   // |v| >= 16
    atomicAdd(&cnt, local);
    __syncthreads();
    if (threadIdx.x == 0) *flag = (cnt > 512) ? 1 : 0;
}

// ---- zero pipeline progress flags each launch (d_ws is poisoned)
__global__ void init_flags(int* __restrict__ prog) {
    prog[threadIdx.x] = 0;   // 256 ints: prog_p[128] | prog_c[128]
}

// =====================================================================
// block p<NP = layer-0 producer; block NP+p = layer-1 consumer+classifier.
// h0 streamed via per-pair ring FIFO (F slots, row-major) in d_ws.
// R8: h0/x staged TWO steps ahead so the input-dependent half of the gate
// MFMAs (wi1f·h0 / x·xbf + bias) is precomputed in the prior step's
// activation window — halves the barrier-to-barrier dependent MFMA chain.
// =====================================================================
__global__ __launch_bounds__(BLK, 2) void lstm2_pipe(
    const void* __restrict__ x,
    const void* __restrict__ wih0, const void* __restrict__ whh0,
    const void* __restrict__ bih0, const void* __restrict__ bhh0,
    const void* __restrict__ wih1, const void* __restrict__ whh1,
    const void* __restrict__ bih1, const void* __restrict__ bhh1,
    const void* __restrict__ cw1, const void* __restrict__ cb1,
    const void* __restrict__ cw2, const void* __restrict__ cb2,
    const int* __restrict__ flag,
    ushort* __restrict__ fifo, int* __restrict__ prog_p, int* __restrict__ prog_c,
    int F, void* __restrict__ out)
{
    __shared__ __align__(16) ushort sA[2][BT * H0STR]; // prod: h0 + x(2-ahead); cons: h0 stage (2-ahead)
    __shared__ __align__(16) ushort sB[2][BT * H1STR]; // cons: h1 recurrence
    __shared__ float rs[BT * 64];                      // cons: classifier hidden

    const bool m32 = (*flag) != 0;
    const int tid  = threadIdx.x;
    const int w    = tid >> 6;
    const int lane = tid & 63;
    const int quad = lane >> 4;
    const int l16  = lane & 15;

    if ((int)blockIdx.x < NP) {
        // ================= PRODUCER: layer 0 =================
        const int p   = blockIdx.x;
        const int bt0 = p * BT;
        ushort* myfifo = fifo + (long)p * F * (BT * H_);

        // stage x(0) into sA[0], x(1) into sA[1] (x region = cols 128..159)
        for (int i = tid; i < BT * 32; i += BLK) {
            int row = i >> 5, cc = i & 31;
            ushort v0 = 0, v1 = 0;
            if (cc < 5) {
                v0 = f2b(ldf(x, ((long)(bt0 + row) * T_ + 0) * D_ + cc, m32));
                v1 = f2b(ldf(x, ((long)(bt0 + row) * T_ + 1) * D_ + cc, m32));
            }
            sA[0][row * H0STR + 128 + cc] = v0;
            sA[1][row * H0STR + 128 + cc] = v1;
        }

        // weights: w_hh0 frags + x-tile frags (~140 regs/wave)
        bf16x8 wh0c[4][4];
        bf16x8 xbf[4];
        float  b0v[4];
#pragma unroll
        for (int g = 0; g < 4; ++g) {
            const int n = g * 128 + w * 16 + l16;
#pragma unroll
            for (int kt = 0; kt < 4; ++kt)
                wh0c[g][kt] = ldfrag(whh0, (long)n * 128 + kt * 32 + quad * 8, m32);
            union { ushort u[8]; bf16x8 v; } xt;
#pragma unroll
            for (int j = 0; j < 8; ++j) xt.u[j] = 0;
            if (quad == 0) {
#pragma unroll
                for (int j = 0; j < 5; ++j) xt.u[j] = f2b(ldf(wih0, (long)n * D_ + j, m32));
            }
            xbf[g] = xt.v;
            b0v[g] = ldf(bih0, n, m32) + ldf(bhh0, n, m32);
        }
        __syncthreads();

        // xP(0) = b0 + x(0)-part, precomputed
        f32x4 xP[4];
        {
            bf16x8 ha0 = ld16(&sA[0][l16 * H0STR + 128 + quad * 8]);
#pragma unroll
            for (int g = 0; g < 4; ++g) {
                xP[g] = splat4(b0v[g]);
                xP[g] = __builtin_amdgcn_mfma_f32_16x16x32_bf16(ha0, xbf[g], xP[g], 0, 0, 0);
            }
        }

        bf16x8 h0f[4];
        {
            uint4 z = make_uint4(0, 0, 0, 0);
            h0f[0] = h0f[1] = h0f[2] = h0f[3] = __builtin_bit_cast(bf16x8, z); // h0(-1)=0
        }
        f32x4 c0 = splat4(0.f);
        const int xr = tid / 5, xc = tid - (tid / 5) * 5;
        long xoff = ((long)(bt0 + xr) * T_ + 2) * D_ + xc;   // x(t+2) pointer-bump
        const int fbase = w * 16 + l16;
        const int frow0 = quad * 4;

#pragma unroll 1
        for (int t = 0; t < T_; ++t) {
            const int wb = (t + 1) & 1;
            if ((t & (CH - 1)) == 0 && t > 0) {
                if (tid == 0) {
                    __hip_atomic_store(&prog_p[p], t, __ATOMIC_RELEASE,
                                       __HIP_MEMORY_SCOPE_AGENT);
                    int need = t + CH - F;   // ring WAR throttle
                    if (need > 0)
                        while (__hip_atomic_load(&prog_c[p], __ATOMIC_ACQUIRE,
                                                 __HIP_MEMORY_SCOPE_AGENT) < need)
                            __builtin_amdgcn_s_sleep(2);
                }
                __syncthreads();
            }
            // off-path: load x(t+2)
            float xv = 0.f;
            const bool stage = (tid < 80) && (t < T_ - 2);
            if (stage) { xv = ldf(x, xoff, m32); xoff += D_; }

            // ---- hot: a = xP(t) + whh0·h0(t-1)
            f32x4 a[4];
#pragma unroll
            for (int g = 0; g < 4; ++g) a[g] = xP[g];
#pragma unroll
            for (int kt = 0; kt < 4; ++kt)
#pragma unroll
                for (int g = 0; g < 4; ++g)
                    a[g] = __builtin_amdgcn_mfma_f32_16x16x32_bf16(
                        h0f[kt], wh0c[g][kt], a[g], 0, 0, 0);
            ushort* fs = myfifo + ((long)(t & (F - 1)) * (BT * H_));
#pragma unroll
            for (int r = 0; r < 4; ++r) {
                float iv = sigf(a[0][r]), fv = sigf(a[1][r]);
                float gv = tanhf_(a[2][r]), ov = sigf(a[3][r]);
                float cv = fv * c0[r] + iv * gv;
                c0[r] = cv;
                ushort hv = f2b(ov * tanhf_(cv));
                sA[wb][(frow0 + r) * H0STR + fbase] = hv;
                fs[(frow0 + r) * H_ + fbase] = hv;        // FIFO (drained by barrier)
            }
            if (stage) sA[t & 1][xr * H0STR + 128 + xc] = f2b(xv); // x(t+2)

            // pre-barrier precompute: xP(t+1) from x(t+1) (staged at t-1, visible)
            {
                bf16x8 ha = ld16(&sA[wb][l16 * H0STR + 128 + quad * 8]);
#pragma unroll
                for (int g = 0; g < 4; ++g) {
                    xP[g] = splat4(b0v[g]);
                    xP[g] = __builtin_amdgcn_mfma_f32_16x16x32_bf16(ha, xbf[g], xP[g], 0, 0, 0);
                }
            }
            __syncthreads();
#pragma unroll
            for (int kt = 0; kt < 4; ++kt)
                h0f[kt] = ld16(&sA[wb][l16 * H0STR + kt * 32 + quad * 8]); // h0(t)
        }
        if (tid == 0)
            __hip_atomic_store(&prog_p[p], T_, __ATOMIC_RELEASE,
                               __HIP_MEMORY_SCOPE_AGENT);
    } else {
        // ================= CONSUMER: layer 1 + classifier =================
        const int p   = blockIdx.x - NP;
        const int bt0 = p * BT;
        const ushort* myfifo = fifo + (long)p * F * (BT * H_);

        // zero h1(-1)
        for (int i = tid; i < BT * H_; i += BLK) {
            int row = i >> 7, cc = i & 127;
            sB[0][row * H1STR + cc] = 0;
        }

        // weights: w_ih1 + w_hh1 frags (~210 regs/wave incl. working set)
        bf16x8 wi1f[4][4], wh1f[4][4];
        float  b1v[4];
#pragma unroll
        for (int g = 0; g < 4; ++g) {
            const int n = g * 128 + w * 16 + l16;
#pragma unroll
            for (int kt = 0; kt < 4; ++kt) {
                wi1f[g][kt] = ldfrag(wih1, (long)n * 128 + kt * 32 + quad * 8, m32);
                wh1f[g][kt] = ldfrag(whh1, (long)n * 128 + kt * 32 + quad * 8, m32);
            }
            b1v[g] = ldf(bih1, n, m32) + ldf(bhh1, n, m32);
        }

        // wait for first two chunks, then stage h0(0) and h0(1)
        if (tid == 0) {
            while (__hip_atomic_load(&prog_p[p], __ATOMIC_ACQUIRE,
                                     __HIP_MEMORY_SCOPE_AGENT) < 2 * CH)
                __builtin_amdgcn_s_sleep(2);
        }
        __syncthreads();
        {
            int row = tid >> 5, col4 = (tid & 31) * 4;
            uint2 d0 = *(const uint2*)(myfifo + tid * 4);
            uint2 d1 = *(const uint2*)(myfifo + (long)(BT * H_) + tid * 4);
            *(uint2*)&sA[0][row * H0STR + col4] = d0;
            *(uint2*)&sA[1][row * H0STR + col4] = d1;
        }
        __syncthreads();

        // P(0) = b1 + wi1f·h0(0)
        f32x4 P[4];
        {
            bf16x8 h0A[4];
#pragma unroll
            for (int kt = 0; kt < 4; ++kt)
                h0A[kt] = ld16(&sA[0][l16 * H0STR + kt * 32 + quad * 8]);
#pragma unroll
            for (int g = 0; g < 4; ++g) P[g] = splat4(b1v[g]);
#pragma unroll
            for (int kt = 0; kt < 4; ++kt)
#pragma unroll
                for (int g = 0; g < 4; ++g)
                    P[g] = __builtin_amdgcn_mfma_f32_16x16x32_bf16(
                        h0A[kt], wi1f[g][kt], P[g], 0, 0, 0);
        }

        f32x4 c1 = splat4(0.f);
        const int srow = tid >> 5, scol4 = (tid & 31) * 4;

#pragma unroll 1
        for (int t = 0; t < T_; ++t) {
            const int rb = t & 1, wb = (t + 1) & 1;
            // chunk boundary BEFORE prefetching slot t+2 of the next chunk
            if (((t + 2) & (CH - 1)) == 0) {
                if (tid == 0) {
                    int target = t + 2 + CH;
                    if (target > T_) target = T_;
                    while (__hip_atomic_load(&prog_p[p], __ATOMIC_ACQUIRE,
                                             __HIP_MEMORY_SCOPE_AGENT) < target)
                        __builtin_amdgcn_s_sleep(2);
                    __hip_atomic_store(&prog_c[p], t, __ATOMIC_RELEASE,
                                       __HIP_MEMORY_SCOPE_AGENT);
                }
                __syncthreads();
            }
            // off-path: prefetch h0(t+2) (global, 2 steps deep)
            uint2 pf = make_uint2(0, 0);
            const bool hn = (t + 2 < T_);
            if (hn) pf = *(const uint2*)(myfifo
                          + (long)((t + 2) & (F - 1)) * (BT * H_) + tid * 4);

            // ---- hot: a = P(t) + wh1f·h1(t-1)
            f32x4 a[4];
#pragma unroll
            for (int g = 0; g < 4; ++g) a[g] = P[g];
#pragma unroll
            for (int kt = 0; kt < 4; ++kt) {
                bf16x8 hb = ld16(&sB[rb][l16 * H1STR + kt * 32 + quad * 8]);
#pragma unroll
                for (int g = 0; g < 4; ++g)
                    a[g] = __builtin_amdgcn_mfma_f32_16x16x32_bf16(
                        hb, wh1f[g][kt], a[g], 0, 0, 0);
            }
#pragma unroll
            for (int r = 0; r < 4; ++r) {
                float iv = sigf(a[0][r]), fv = sigf(a[1][r]);
                float gv = tanhf_(a[2][r]), ov = sigf(a[3][r]);
                float cv = fv * c1[r] + iv * gv;
                c1[r] = cv;
                sB[wb][(quad * 4 + r) * H1STR + w * 16 + l16] = f2b(ov * tanhf_(cv));
            }
            // off-path: stage h0(t+2) into sA[t&1] (h0(t) consumed for P(t) at t-1)
            if (hn) *(uint2*)&sA[t & 1][srow * H0STR + scol4] = pf;

            // pre-barrier precompute: P(t+1) from h0(t+1) (staged at t-1, visible)
            {
                bf16x8 h0A[4];
#pragma unroll
                for (int kt = 0; kt < 4; ++kt)
                    h0A[kt] = ld16(&sA[wb][l16 * H0STR + kt * 32 + quad * 8]);
#pragma unroll
                for (int g = 0; g < 4; ++g) P[g] = splat4(b1v[g]);
#pragma unroll
                for (int kt = 0; kt < 4; ++kt)
#pragma unroll
                    for (int g = 0; g < 4; ++g)
                        P[g] = __builtin_amdgcn_mfma_f32_16x16x32_bf16(
                            h0A[kt], wi1f[g][kt], P[g], 0, 0, 0);
            }
            __syncthreads();
        }

        // h1(T-1) is in sB[0]  (t=511 wrote wb=0)
        if (tid < 256) {
            int m = tid >> 4, j0 = (tid & 15) * 4;
            float s0 = ldf(cb1, j0, m32), s1 = ldf(cb1, j0 + 1, m32);
            float s2 = ldf(cb1, j0 + 2, m32), s3 = ldf(cb1, j0 + 3, m32);
            const ushort* hr = &sB[0][m * H1STR];
#pragma unroll 4
            for (int k = 0; k < 128; ++k) {
                float hv = b2f(hr[k]);
                s0 += hv * ldf(cw1, (long)j0 * 128 + k, m32);
                s1 += hv * ldf(cw1, (long)(j0 + 1) * 128 + k, m32);
                s2 += hv * ldf(cw1, (long)(j0 + 2) * 128 + k, m32);
                s3 += hv * ldf(cw1, (long)(j0 + 3) * 128 + k, m32);
            }
            rs[m * 64 + j0]     = fmaxf(s0, 0.f);
            rs[m * 64 + j0 + 1] = fmaxf(s1, 0.f);
            rs[m * 64 + j0 + 2] = fmaxf(s2, 0.f);
            rs[m * 64 + j0 + 3] = fmaxf(s3, 0.f);
        }
        __syncthreads();
        if (tid < 160) {
            int m = tid / 10, cc = tid - m * 10;
            float s = ldf(cb2, cc, m32);
#pragma unroll
            for (int j = 0; j < 64; ++j)
                s += rs[m * 64 + j] * ldf(cw2, (long)cc * 64 + j, m32);
            long oi = (long)(bt0 + m) * C_ + cc;
            if (m32) ((float*)out)[oi] = s; else ((ushort*)out)[oi] = f2b(s);
        }
        for (int idx = tid; idx < BT * H_; idx += BLK) {
            int m = idx >> 7, k = idx & 127;
            float v = b2f(sB[0][m * H1STR + k]);
            long oi = (long)B_ * C_ + (long)(bt0 + m) * H_ + k;
            if (m32) ((float*)out)[oi] = v; else ((ushort*)out)[oi] = f2b(v);
        }
    }
}

// =====================================================================
// Fallback: proven R5 monolithic kernel (when ws too small for the FIFO)
// =====================================================================
__global__ __launch_bounds__(BLK, 2) void lstm2_mono(
    const void* __restrict__ x,
    const void* __restrict__ wih0, const void* __restrict__ whh0,
    const void* __restrict__ bih0, const void* __restrict__ bhh0,
    const void* __restrict__ wih1, const void* __restrict__ whh1,
    const void* __restrict__ bih1, const void* __restrict__ bhh1,
    const void* __restrict__ cw1, const void* __restrict__ cb1,
    const void* __restrict__ cw2, const void* __restrict__ cb2,
    const int* __restrict__ flag, void* __restrict__ out)
{
    __shared__ __align__(16) ushort h0s[2][BT * H0STR];
    __shared__ __align__(16) ushort h1s[2][BT * H1STR];
    __shared__ float rs[BT * 64];
    __shared__ uint4 xstash[4 * 8 * 64];

    const bool m32 = (*flag) != 0;
    const int tid  = threadIdx.x;
    const int w    = tid >> 6;
    const int lane = tid & 63;
    const int quad = lane >> 4;
    const int l16  = lane & 15;
    const int bt0  = blockIdx.x * BT;

    for (int i = tid; i < BT * 32; i += BLK) {
        int row = i >> 5, cc = i & 31;
        ushort v0 = (cc < 5) ? f2b(ldf(x, ((long)(bt0 + row) * T_) * D_ + cc, m32)) : (ushort)0;
        h0s[0][row * H0STR + 128 + cc] = v0;
        h0s[1][row * H0STR + 128 + cc] = 0;
    }
    for (int i = tid; i < BT * H_; i += BLK) {
        int row = i >> 7, cc = i & 127;
        h1s[1][row * H1STR + cc] = 0;
    }

    bf16x8 wh0c[4][4], wi1f[4][4], wh1f[4][4];
    float  b0v[4], b1v[4];
#pragma unroll
    for (int g = 0; g < 4; ++g) {
        const int n = g * 128 + w * 16 + l16;
#pragma unroll
        for (int kt = 0; kt < 4; ++kt) {
            wh0c[g][kt] = ldfrag(whh0, (long)n * 128 + kt * 32 + quad * 8, m32);
            wi1f[g][kt] = ldfrag(wih1, (long)n * 128 + kt * 32 + quad * 8, m32);
            wh1f[g][kt] = ldfrag(whh1, (long)n * 128 + kt * 32 + quad * 8, m32);
        }
        union { ushort u[8]; uint4 q; } xt;
        xt.q = make_uint4(0, 0, 0, 0);
        if (quad == 0) {
#pragma unroll
            for (int j = 0; j < 5; ++j) xt.u[j] = f2b(ldf(wih0, (long)n * D_ + j, m32));
        }
        xstash[(g * 8 + w) * 64 + lane] = xt.q;
        b0v[g] = ldf(bih0, n, m32) + ldf(bhh0, n, m32);
        b1v[g] = ldf(bih1, n, m32) + ldf(bhh1, n, m32);
    }
    __syncthreads();

    bf16x8 h0f[4];
    {
        uint4 z = make_uint4(0, 0, 0, 0);
        h0f[0] = h0f[1] = h0f[2] = h0f[3] = __builtin_bit_cast(bf16x8, z);
    }
    f32x4 c0 = splat4(0.f), c1 = splat4(0.f);
    const int xr = tid / 5, xc = tid - (tid / 5) * 5;

#pragma unroll 1
    for (int t = 0; t < T_; ++t) {
        const int wb = (t + 1) & 1, rb = t & 1;
        float xv = 0.f;
        const bool stage = (tid < 80) && (t < T_ - 1);
        if (stage) xv = ldf(x, ((long)(bt0 + xr) * T_ + (t + 1)) * D_ + xc, m32);

        f32x4 a[4];
#pragma unroll
        for (int g = 0; g < 4; ++g) a[g] = splat4(b0v[g]);
#pragma unroll
        for (int kt = 0; kt < 4; ++kt)
#pragma unroll
            for (int g = 0; g < 4; ++g)
                a[g] = __builtin_amdgcn_mfma_f32_16x16x32_bf16(
                    h0f[kt], wh0c[g][kt], a[g], 0, 0, 0);
        {
            bf16x8 ha4 = ld16(&h0s[rb][l16 * H0STR + 128 + quad * 8]);
#pragma unroll
            for (int g = 0; g < 4; ++g) {
                bf16x8 xb = __builtin_bit_cast(bf16x8, xstash[(g * 8 + w) * 64 + lane]);
                a[g] = __builtin_amdgcn_mfma_f32_16x16x32_bf16(ha4, xb, a[g], 0, 0, 0);
            }
        }
        ushort h0w[4];
#pragma unroll
        for (int r = 0; r < 4; ++r) {
            float iv = sigf(a[0][r]), fv = sigf(a[1][r]);
            float gv = tanhf_(a[2][r]), ov = sigf(a[3][r]);
            float cv = fv * c0[r] + iv * gv;
            c0[r] = cv;
            h0w[r] = f2b(ov * tanhf_(cv));
        }
#pragma unroll
        for (int r = 0; r < 4; ++r)
            h0s[wb][(quad * 4 + r) * H0STR + w * 16 + l16] = h0w[r];
        if (stage) h0s[wb][xr * H0STR + 128 + xc] = f2b(xv);
        __syncthreads();
#pragma unroll
        for (int kt = 0; kt < 4; ++kt)
            h0f[kt] = ld16(&h0s[wb][l16 * H0STR + kt * 32 + quad * 8]);

#pragma unroll
        for (int g = 0; g < 4; ++g) a[g] = splat4(b1v[g]);
#pragma unroll
        for (int kt = 0; kt < 4; ++kt)
#pragma unroll
            for (int g = 0; g < 4; ++g)
                a[g] = __builtin_amdgcn_mfma_f32_16x16x32_bf16(
                    h0f[kt], wi1f[g][kt], a[g], 0, 0, 0);
#pragma unroll
        for (int kt = 0; kt < 4; ++kt) {
            bf16x8 hb = ld16(&h1s[wb][l16 * H1STR + kt * 32 + quad * 8]);
#pragma unroll
            for (int g = 0; g < 4; ++g)
                a[g] = __builtin_amdgcn_mfma_f32_16x16x32_bf16(
                    hb, wh1f[g][kt], a[g], 0, 0, 0);
        }
#pragma unroll
        for (int r = 0; r < 4; ++r) {
            float iv = sigf(a[0][r]), fv = sigf(a[1][r]);
            float gv = tanhf_(a[2][r]), ov = sigf(a[3][r]);
            float cv = fv * c1[r] + iv * gv;
            c1[r] = cv;
            h1s[wb ^ 1][(quad * 4 + r) * H1STR + w * 16 + l16] = f2b(ov * tanhf_(cv));
        }
    }
    __syncthreads();

    if (tid < 256) {
        int m = tid >> 4, j0 = (tid & 15) * 4;
        float s0 = ldf(cb1, j0, m32), s1 = ldf(cb1, j0 + 1, m32);
        float s2 = ldf(cb1, j0 + 2, m32), s3 = ldf(cb1, j0 + 3, m32);
        const ushort* hr = &h1s[1][m * H1STR];
#pragma unroll 4
        for (int k = 0; k < 128; ++k) {
            float hv = b2f(hr[k]);
            s0 += hv * ldf(cw1, (long)j0 * 128 + k, m32);
            s1 += hv * ldf(cw1, (long)(j0 + 1) * 128 + k, m32);
            s2 += hv * ldf(cw1, (long)(j0 + 2) * 128 + k, m32);
            s3 += hv * ldf(cw1, (long)(j0 + 3) * 128 + k, m32);
        }
        rs[m * 64 + j0]     = fmaxf(s0, 0.f);
        rs[m * 64 + j0 + 1] = fmaxf(s1, 0.f);
        rs[m * 64 + j0 + 2] = fmaxf(s2, 0.f);
        rs[m * 64 + j0 + 3] = fmaxf(s3, 0.f);
    }
    __syncthreads();
    if (tid < 160) {
        int m = tid / 10, cc = tid - m * 10;
        float s = ldf(cb2, cc, m32);
#pragma unroll
        for (int j = 0; j < 64; ++j) s += rs[m * 64 + j] * ldf(cw2, (long)cc * 64 + j, m32);
        long oi = (long)(bt0 + m) * C_ + cc;
        if (m32) ((float*)out)[oi] = s; else ((ushort*)out)[oi] = f2b(s);
    }
    for (int idx = tid; idx < BT * H_; idx += BLK) {
        int m = idx >> 7, k = idx & 127;
        float v = b2f(h1s[1][m * H1STR + k]);
        long oi = (long)B_ * C_ + (long)(bt0 + m) * H_ + k;
        if (m32) ((float*)out)[oi] = v; else ((ushort*)out)[oi] = f2b(v);
    }
}

extern "C" void kernel_launch(void* const* d_in, const int* in_sizes, int n_in,
                              void* d_out, int out_size, void* d_ws, size_t ws_size,
                              hipStream_t stream) {
    (void)in_sizes; (void)n_in; (void)out_size;
    int* prog  = (int*)d_ws;                       // prog_p[128] | prog_c[128]
    int* flag  = (int*)((char*)d_ws + 4096);
    ushort* fifo = (ushort*)((char*)d_ws + 8192);

    hipLaunchKernelGGL(detect_dtype, dim3(1), dim3(256), 0, stream,
                       (const ushort*)d_in[2], flag);

    const size_t slot = (size_t)NP * BT * H_ * sizeof(ushort); // all pairs, 1 step
    int F = 0;
    if (ws_size >= 8192 + 64 * slot) F = 64;

    if (F) {
        hipLaunchKernelGGL(init_flags, dim3(1), dim3(256), 0, stream, prog);
        hipLaunchKernelGGL(lstm2_pipe, dim3(2 * NP), dim3(BLK), 0, stream,
                           d_in[0], d_in[1], d_in[2], d_in[3], d_in[4],
                           d_in[5], d_in[6], d_in[7], d_in[8],
                           d_in[9], d_in[10], d_in[11], d_in[12],
                           (const int*)flag, fifo, prog, prog + NP, F, d_out);
    } else {
        hipLaunchKernelGGL(lstm2_mono, dim3(B_ / BT), dim3(BLK), 0, stream,
                           d_in[0], d_in[1], d_in[2], d_in[3], d_in[4],
                           d_in[5], d_in[6], d_in[7], d_in[8],
                           d_in[9], d_in[10], d_in[11], d_in[12],
                           (const int*)flag, d_out);
    }
}